// Round 1
// baseline (82.951 us; speedup 1.0000x reference)
//
#include <hip/hip_runtime.h>

// SoftNCutLoss: image [4,3,256,256] f32, enc [4,4,256,256] f32 -> scalar f32.
// Key insight: dsq <= RADIUS(=5) mask leaves only 21 active offsets (|dy|,|dx| <= 2).

static constexpr int NOFF = 21;

__device__ __constant__ int   c_dy[NOFF] = {-2,-2,-2, -1,-1,-1,-1,-1, 0,0,0,0,0, 1,1,1,1,1, 2,2,2};
__device__ __constant__ int   c_dx[NOFF] = {-1, 0, 1, -2,-1, 0, 1, 2, -2,-1,0,1,2, -2,-1,0,1,2, -1,0,1};
// dw = exp(-dsq/16) for dsq = dy^2+dx^2
__device__ __constant__ float c_dw[NOFF] = {
    0.73161563f, 0.77880078f, 0.73161563f,
    0.73161563f, 0.88249690f, 0.93941306f, 0.88249690f, 0.73161563f,
    0.77880078f, 0.93941306f, 1.00000000f, 0.93941306f, 0.77880078f,
    0.73161563f, 0.88249690f, 0.93941306f, 0.88249690f, 0.73161563f,
    0.73161563f, 0.77880078f, 0.73161563f};

// accum layout in d_ws (floats): [0..15] num[b*4+k], [16..31] den[b*4+k]

__global__ __launch_bounds__(256) void snc_main(const float* __restrict__ img,
                                                const float* __restrict__ enc,
                                                float* __restrict__ accum) {
    const int b   = blockIdx.x >> 8;                       // 256 blocks per batch
    const int pix = ((blockIdx.x & 255) << 8) | threadIdx.x;
    const int h = pix >> 8;
    const int w = pix & 255;

    const float* __restrict__ imgb = img + b * 3 * 65536;
    const float* __restrict__ encb = enc + b * 4 * 65536;

    // gray at center
    const float c = (imgb[pix] + imgb[65536 + pix] + imgb[131072 + pix]) * (1.0f / 3.0f);

    float wsum = 0.0f;
    float nom0 = 0.0f, nom1 = 0.0f, nom2 = 0.0f, nom3 = 0.0f;

#pragma unroll
    for (int i = 0; i < NOFF; ++i) {
        const int hh = h + c_dy[i];
        const int ww = w + c_dx[i];
        const bool inb = ((unsigned)hh < 256u) && ((unsigned)ww < 256u);
        float g = 0.0f, e0 = 0.0f, e1 = 0.0f, e2 = 0.0f, e3 = 0.0f;
        if (inb) {
            const int o = (hh << 8) | ww;
            g = (imgb[o] + imgb[65536 + o] + imgb[131072 + o]) * (1.0f / 3.0f);
            e0 = encb[o];
            e1 = encb[65536 + o];
            e2 = encb[131072 + o];
            e3 = encb[196608 + o];
        }
        const float d  = g - c;
        const float wg = expf(d * d * -0.01f) * c_dw[i];   // exp(-(d^2)/OI^2), OI=10
        wsum += wg;
        nom0 += wg * e0;
        nom1 += wg * e1;
        nom2 += wg * e2;
        nom3 += wg * e3;
    }

    // per-pixel contributions to num[b,k] and den[b,k]
    const float ec0 = encb[pix];
    const float ec1 = encb[65536 + pix];
    const float ec2 = encb[131072 + pix];
    const float ec3 = encb[196608 + pix];

    float v[8];
    v[0] = ec0 * nom0;  v[1] = ec1 * nom1;  v[2] = ec2 * nom2;  v[3] = ec3 * nom3;
    v[4] = ec0 * wsum;  v[5] = ec1 * wsum;  v[6] = ec2 * wsum;  v[7] = ec3 * wsum;

    // wave64 shuffle reduce all 8 values
#pragma unroll
    for (int off = 32; off; off >>= 1) {
#pragma unroll
        for (int j = 0; j < 8; ++j) v[j] += __shfl_down(v[j], off);
    }

    __shared__ float part[4][8];
    const int wave = threadIdx.x >> 6;
    const int lane = threadIdx.x & 63;
    if (lane == 0) {
#pragma unroll
        for (int j = 0; j < 8; ++j) part[wave][j] = v[j];
    }
    __syncthreads();

    if (threadIdx.x < 8) {
        const int j = threadIdx.x;
        const float p = part[0][j] + part[1][j] + part[2][j] + part[3][j];
        const int idx = (j < 4) ? (b * 4 + j) : (16 + b * 4 + (j - 4));
        atomicAdd(&accum[idx], p);
    }
}

__global__ void snc_final(const float* __restrict__ accum, float* __restrict__ out) {
    if (threadIdx.x == 0 && blockIdx.x == 0) {
        float loss = 0.0f;
#pragma unroll
        for (int b = 0; b < 4; ++b) {
            float s = 0.0f;
#pragma unroll
            for (int k = 0; k < 4; ++k)
                s += accum[b * 4 + k] / (accum[16 + b * 4 + k] + 1e-8f);
            loss += (4.0f - s);
        }
        out[0] = loss * 0.25f;
    }
}

extern "C" void kernel_launch(void* const* d_in, const int* in_sizes, int n_in,
                              void* d_out, int out_size, void* d_ws, size_t ws_size,
                              hipStream_t stream) {
    const float* img = (const float*)d_in[0];   // [4,3,256,256]
    const float* enc = (const float*)d_in[1];   // [4,4,256,256]
    float* out   = (float*)d_out;               // scalar
    float* accum = (float*)d_ws;                // 32 floats

    hipMemsetAsync(accum, 0, 32 * sizeof(float), stream);
    snc_main<<<dim3(1024), dim3(256), 0, stream>>>(img, enc, accum);
    snc_final<<<dim3(1), dim3(64), 0, stream>>>(accum, out);
}

// Round 2
// 68.837 us; speedup vs baseline: 1.2050x; 1.2050x over previous
//
#include <hip/hip_runtime.h>

// SoftNCutLoss: image [4,3,256,256] f32, enc [4,4,256,256] f32 -> scalar f32.
// dsq <= RADIUS(=5) mask leaves only 21 active offsets (|dy|,|dx| <= 2).
// R1: LDS-staged halo tiles (gray + enc-as-float4), __expf, block-slot
//     partials in d_ws (no memset, no atomics).

static constexpr int NOFF = 21;

__device__ __constant__ int   c_dy[NOFF] = {-2,-2,-2, -1,-1,-1,-1,-1, 0,0,0,0,0, 1,1,1,1,1, 2,2,2};
__device__ __constant__ int   c_dx[NOFF] = {-1, 0, 1, -2,-1, 0, 1, 2, -2,-1,0,1,2, -2,-1,0,1,2, -1,0,1};
// dw = exp(-dsq/16) for dsq = dy^2+dx^2
__device__ __constant__ float c_dw[NOFF] = {
    0.73161563f, 0.77880078f, 0.73161563f,
    0.73161563f, 0.88249690f, 0.93941306f, 0.88249690f, 0.73161563f,
    0.77880078f, 0.93941306f, 1.00000000f, 0.93941306f, 0.77880078f,
    0.73161563f, 0.88249690f, 0.93941306f, 0.88249690f, 0.73161563f,
    0.73161563f, 0.77880078f, 0.73161563f};

// d_ws layout: part[1024][8] floats = 32 KB. Block g writes part[g][0..7] =
// {num0..num3, den0..den3} (its batch's partial sums).

#define TILE   16
#define HALO   2
#define TW     (TILE + 2 * HALO)          // 20
#define TP     (TW + 1)                   // 21, padded row stride

__global__ __launch_bounds__(256) void snc_main(const float* __restrict__ img,
                                                const float* __restrict__ enc,
                                                float* __restrict__ part) {
    __shared__ float  sGray[TW * TP];
    __shared__ float4 sEnc [TW * TP];

    const int b    = blockIdx.x >> 8;            // 256 tiles per batch
    const int tile = blockIdx.x & 255;
    const int ph   = (tile >> 4) << 4;           // tile origin
    const int pw   = (tile & 15) << 4;

    const float* __restrict__ imgb = img + b * 3 * 65536;
    const float* __restrict__ encb = enc + b * 4 * 65536;

    const int tid = threadIdx.x;

    // ---- stage 20x20 halo tile: gray (mean of 3 ch) + enc float4 ----
#pragma unroll
    for (int i = tid; i < TW * TW; i += 256) {
        const int gy = i / TW;
        const int gx = i - gy * TW;
        const int hh = ph + gy - HALO;
        const int ww = pw + gx - HALO;
        const bool inb = ((unsigned)hh < 256u) && ((unsigned)ww < 256u);
        float g = 0.0f;
        float4 e = make_float4(0.0f, 0.0f, 0.0f, 0.0f);
        if (inb) {
            const int o = (hh << 8) | ww;
            g = (imgb[o] + imgb[65536 + o] + imgb[131072 + o]) * (1.0f / 3.0f);
            e.x = encb[o];
            e.y = encb[65536 + o];
            e.z = encb[131072 + o];
            e.w = encb[196608 + o];
        }
        sGray[gy * TP + gx] = g;
        sEnc [gy * TP + gx] = e;
    }
    __syncthreads();

    // ---- per-pixel bilateral accumulation (branchless, all from LDS) ----
    const int ly = tid >> 4;                     // 0..15
    const int lx = tid & 15;
    const int ctr = (ly + HALO) * TP + (lx + HALO);

    const float  c  = sGray[ctr];
    const float4 ec = sEnc[ctr];

    float wsum = 0.0f;
    float nom0 = 0.0f, nom1 = 0.0f, nom2 = 0.0f, nom3 = 0.0f;

#pragma unroll
    for (int i = 0; i < NOFF; ++i) {
        const int idx = ctr + c_dy[i] * TP + c_dx[i];
        const float  g = sGray[idx];
        const float4 e = sEnc[idx];
        const float  d = g - c;
        const float wg = __expf(d * d * -0.01f) * c_dw[i];   // exp(-d^2/100)
        wsum += wg;
        nom0 += wg * e.x;
        nom1 += wg * e.y;
        nom2 += wg * e.z;
        nom3 += wg * e.w;
    }

    float v[8];
    v[0] = ec.x * nom0;  v[1] = ec.y * nom1;  v[2] = ec.z * nom2;  v[3] = ec.w * nom3;
    v[4] = ec.x * wsum;  v[5] = ec.y * wsum;  v[6] = ec.z * wsum;  v[7] = ec.w * wsum;

    // wave64 shuffle reduce
#pragma unroll
    for (int off = 32; off; off >>= 1) {
#pragma unroll
        for (int j = 0; j < 8; ++j) v[j] += __shfl_down(v[j], off);
    }

    __shared__ float red[4][8];
    const int wave = tid >> 6;
    const int lane = tid & 63;
    if (lane == 0) {
#pragma unroll
        for (int j = 0; j < 8; ++j) red[wave][j] = v[j];
    }
    __syncthreads();

    if (tid < 8) {
        part[blockIdx.x * 8 + tid] =
            red[0][tid] + red[1][tid] + red[2][tid] + red[3][tid];
    }
}

__global__ __launch_bounds__(256) void snc_final(const float* __restrict__ part,
                                                 float* __restrict__ out) {
    const int t    = threadIdx.x;
    const int b    = t >> 6;                     // one wave per batch
    const int lane = t & 63;

    float v[8];
#pragma unroll
    for (int j = 0; j < 8; ++j) v[j] = 0.0f;
#pragma unroll
    for (int i = 0; i < 4; ++i) {
        const float* p = part + (size_t)(b * 256 + i * 64 + lane) * 8;
#pragma unroll
        for (int j = 0; j < 8; ++j) v[j] += p[j];
    }
#pragma unroll
    for (int off = 32; off; off >>= 1) {
#pragma unroll
        for (int j = 0; j < 8; ++j) v[j] += __shfl_down(v[j], off);
    }

    __shared__ float res[4];
    if (lane == 0) {
        float s = 0.0f;
#pragma unroll
        for (int k = 0; k < 4; ++k) s += v[k] / (v[4 + k] + 1e-8f);
        res[b] = 4.0f - s;
    }
    __syncthreads();
    if (t == 0) out[0] = (res[0] + res[1] + res[2] + res[3]) * 0.25f;
}

extern "C" void kernel_launch(void* const* d_in, const int* in_sizes, int n_in,
                              void* d_out, int out_size, void* d_ws, size_t ws_size,
                              hipStream_t stream) {
    const float* img = (const float*)d_in[0];   // [4,3,256,256]
    const float* enc = (const float*)d_in[1];   // [4,4,256,256]
    float* out  = (float*)d_out;                // scalar
    float* part = (float*)d_ws;                 // [1024][8] floats

    snc_main<<<dim3(1024), dim3(256), 0, stream>>>(img, enc, part);
    snc_final<<<dim3(1), dim3(256), 0, stream>>>(part, out);
}